// Round 20
// baseline (409.791 us; speedup 1.0000x reference)
//
#include <hip/hip_runtime.h>
#include <hip/hip_bf16.h>
#include <stdint.h>

#define N_NODES 100000
#define N_EDGES 1600000
#define HID 128
#define OUT_DIM 64
#define N_LAYERS 3
#define CAP 64        // ELL row capacity (slots per node); deg~Poisson(16)
#define CAP_SHIFT 6
#define BIN_NODES 256 // dst nodes per bin (phase-1 packing granule)
#define NBIN2 ((N_NODES + BIN_NODES - 1) / BIN_NODES)   // 391
#define BINCAP 8192   // u32 edge slots per bin (mean ~4092, Poisson-tight)
#define CNT_STRIDE 16 // bin_cnt padded: one counter per 64B line (no false sharing)
#define EPT 32        // edges per thread in fill phase (8192/block)
#define P1_BLOCKS ((N_EDGES + 256 * EPT - 1) / (256 * EPT))   // 196

typedef __attribute__((ext_vector_type(8))) short short8;
typedef __attribute__((ext_vector_type(4))) float v4f;
typedef __attribute__((ext_vector_type(4))) unsigned short ushort4v;

__device__ __forceinline__ float bf2f(unsigned int lo16) {
    union { unsigned int i; float f; } v; v.i = lo16 << 16; return v.f;
}
__device__ __forceinline__ unsigned short f2bf(float f) {
    union { float f; unsigned int i; } v; v.f = f;
    unsigned int r = v.i + 0x7fffu + ((v.i >> 16) & 1u);  // RNE
    return (unsigned short)(r >> 16);
}

// async global->LDS, 16B per lane; LDS dest = wave-uniform base + lane*16,
// global src is per-lane (rule #21: swizzle goes on the SOURCE + the READ).
__device__ __forceinline__ void stage16(const void* g, void* l) {
    __builtin_amdgcn_global_load_lds(
        (const __attribute__((address_space(1))) unsigned int*)g,
        (__attribute__((address_space(3))) unsigned int*)l, 16, 0, 0);
}

// ---------------- merged prologue + fill phase 1 --------------------------
// R17-verified: EPT32 + line-padded bin_cnt (atomic-chain + false-sharing
// fixes totaled -19.7us over R16/R17).
#define CONV_N (N_NODES * HID / 4)
__global__ __launch_bounds__(256) void merged_pre(
    const int* __restrict__ raw,
    int* __restrict__ bin_cnt, unsigned int* __restrict__ bins,
    const float* __restrict__ x, unsigned short* __restrict__ xb,
    const float* __restrict__ Wl, const float* __restrict__ Wr,
    const float* __restrict__ fc_w,
    unsigned short* __restrict__ WlT, unsigned short* __restrict__ WrT,
    unsigned short* __restrict__ fcT,
    unsigned short* b0, unsigned short* b1, unsigned short* b2) {
    __shared__ int h[NBIN2];
    __shared__ int basekeep[NBIN2];
    __shared__ int sflag;
    int blk = blockIdx.x, tid = threadIdx.x;

    if (blk < P1_BLOCKS) {
        if (tid < 64) {
            int v = raw[2 * tid + 1];           // odd dwords = int64 high words
            unsigned long long bl = __ballot(v != 0);
            if (tid == 0) sflag = (bl == 0ull) ? 1 : 0;
        }
        for (int b = tid; b < NBIN2; b += 256) h[b] = 0;
        __syncthreads();
        bool is64 = (sflag != 0);

        int e0 = blk * (256 * EPT) + tid;
        int s[EPT], d[EPT];
#pragma unroll
        for (int k = 0; k < EPT; ++k) {
            int e = e0 + k * 256;
            if (e < N_EDGES) {
                if (is64) {
                    const long long* r = (const long long*)raw;
                    d[k] = (int)r[N_EDGES + e];
                    s[k] = (int)r[e];
                } else {
                    d[k] = raw[N_EDGES + e];
                    s[k] = raw[e];
                }
            } else {
                d[k] = -1;
            }
        }
#pragma unroll
        for (int k = 0; k < EPT; ++k)
            if (d[k] >= 0) atomicAdd(&h[d[k] >> 8], 1);
        __syncthreads();
        for (int b = tid; b < NBIN2; b += 256) {
            int c = h[b];
            basekeep[b] = c ? atomicAdd(&bin_cnt[b * CNT_STRIDE], c) : 0;
            h[b] = 0;   // reuse as block-local write cursor
        }
        __syncthreads();
#pragma unroll
        for (int k = 0; k < EPT; ++k) {
            if (d[k] >= 0) {
                int b = d[k] >> 8;
                int off = basekeep[b] + atomicAdd(&h[b], 1);
                if (off < BINCAP)
                    bins[(size_t)b * BINCAP + off] =
                        ((unsigned int)s[k] << 8) | (unsigned int)(d[k] & 255);
            }
        }
    }

    if (blk == P1_BLOCKS && tid < 192) {        // zero sentinel rows
        unsigned short* bufs[3] = {b0, b1, b2};
        uint32_t* p = (uint32_t*)bufs[tid >> 6];
        p[(size_t)N_NODES * 64 + (tid & 63)] = 0;
    }

    // ---- prep range (all blocks) ----
    int gidx = blk * 256 + tid;
    if (gidx < CONV_N) {
        float4 v = ((const float4*)x)[gidx];
        ushort4v o;
        o[0] = f2bf(v.x); o[1] = f2bf(v.y); o[2] = f2bf(v.z); o[3] = f2bf(v.w);
        ((ushort4v*)xb)[gidx] = o;
    } else {
        int idx = gidx - CONV_N;
        const int WELEMS = N_LAYERS * HID * HID;
        if (idx < WELEMS) {
            int l = idx / (HID * HID);
            int rem = idx - l * HID * HID;
            int k = rem / HID, nn2 = rem - k * HID;
            WlT[l * HID * HID + nn2 * HID + k] = f2bf(Wl[idx]);
            WrT[l * HID * HID + nn2 * HID + k] = f2bf(Wr[idx]);
        } else {
            int j = idx - WELEMS;
            if (j < N_LAYERS * HID * OUT_DIM) {
                int l = j / (HID * OUT_DIM);
                int rem = j - l * HID * OUT_DIM;
                int k = rem / OUT_DIM, o = rem - k * OUT_DIM;
                fcT[l * OUT_DIM * HID + o * HID + k] = f2bf(fc_w[(l * HID + k) * OUT_DIM + o]);
            }
        }
    }
}

// ---------------- fill phase 2: dst-partitioned ELL build in LDS ----------
// Half-bin split (R18/R19, neutral-verified): each block owns 128 nodes
// (32 KB tile, 782 blocks). Both halves scan the full bin segment in the
// SAME order and keep matching edges -> ELL content bit-identical.
__global__ __launch_bounds__(256) void fill_p2(const int* __restrict__ bin_cnt,
                                               const unsigned int* __restrict__ bins,
                                               int* __restrict__ ell,
                                               int* __restrict__ deg,
                                               float* __restrict__ inv_deg, int n) {
    __shared__ int tile[128 * CAP];   // 32 KB
    __shared__ int cnt[128];
    int blk = blockIdx.x, tid = threadIdx.x;
    int b = blk >> 1, half = blk & 1;
    for (int i = tid; i < 128; i += 256) cnt[i] = 0;
    __syncthreads();

    int m = bin_cnt[b * CNT_STRIDE];
    if (m > BINCAP) m = BINCAP;
    for (int i = tid; i < m; i += 256) {
        unsigned int e = bins[(size_t)b * BINCAP + i];
        int dl = (int)(e & 255u);
        if ((dl >> 7) == half) {
            int r = dl & 127;
            int slot = atomicAdd(&cnt[r], 1);
            if (slot < CAP) tile[(r << CAP_SHIFT) + slot] = (int)(e >> 8);
        }
    }
    __syncthreads();

    int node0 = (b << 8) + (half << 7);
    for (int i = tid; i < 128; i += 256) {
        int node = node0 + i;
        if (node < n) {
            int dgf = cnt[i];
            int dg = dgf > CAP ? CAP : dgf;
            deg[node] = dg;
            inv_deg[node] = 1.0f / (float)(dg > 0 ? dg : 1);
            int r = (dg + 7) & ~7;
            for (int p = dg; p < r; ++p) tile[(i << CAP_SHIFT) + p] = N_NODES;
        }
    }
    __syncthreads();

    const uint4* t4 = (const uint4*)tile;    // row = 16 uint4
    uint4* g4 = (uint4*)ell;
    for (int v = tid; v < 128 * 16; v += 256) {
        int row = v >> 4;
        int node = node0 + row;
        if (node < n) g4[((size_t)node << 4) + (v & 15)] = t4[v];
    }
}

// ---------------- mean aggregation: 4 nodes/block, 64-thread blocks -------
// FINAL agg probe: same proven inner loop (7x-confirmed 57.1us/180MB/VGPR44
// signature at 256-thread blocks), but 1-WAVE blocks (grid 25000). The 42%
// occupancy cap has no architectural explanation (VGPR 44 < 64-cliff, LDS
// 0); candidate mechanism is workgroup-slot quantization at 4 waves/block
// (settles at ~3.35 blk/CU = 13.4 waves). 1-wave blocks fill residency in
// 1-wave granularity up to the per-CU slot limit -> potentially 16 waves/CU
// (+19% gather concurrency). Arithmetic & access pattern byte-identical.
__global__ __launch_bounds__(64) void agg_bf(
    const unsigned short* __restrict__ h, const int* __restrict__ ell,
    const int* __restrict__ deg, const float* __restrict__ inv_deg,
    unsigned short* __restrict__ meanb) {
    int tid = threadIdx.x;
    int grp = tid >> 4;          // node slot in block (0..3)
    int lane16 = tid & 15;       // channel octet
    int node = blockIdx.x * 4 + grp;
    bool valid = node < N_NODES;
    int nd = valid ? node : 0;
    int dg = valid ? deg[nd] : 0;
    int dgp = (dg + 7) & ~7;
    int base = nd << CAP_SHIFT;
    const uint4* hv = (const uint4*)h;   // row = 16 uint4
    float a[8];
#pragma unroll
    for (int c = 0; c < 8; ++c) a[c] = 0.f;

    for (int t = 0; t < dgp; t += 8) {
        int idx[8];
#pragma unroll
        for (int u = 0; u < 8; ++u) idx[u] = ell[base + t + u];
        uint4 v[8];
#pragma unroll
        for (int u = 0; u < 8; ++u) v[u] = hv[(size_t)idx[u] * 16 + lane16];
#pragma unroll
        for (int u = 0; u < 8; ++u) {
            a[0] += bf2f(v[u].x & 0xffffu); a[1] += bf2f(v[u].x >> 16);
            a[2] += bf2f(v[u].y & 0xffffu); a[3] += bf2f(v[u].y >> 16);
            a[4] += bf2f(v[u].z & 0xffffu); a[5] += bf2f(v[u].z >> 16);
            a[6] += bf2f(v[u].w & 0xffffu); a[7] += bf2f(v[u].w >> 16);
        }
    }
    if (valid) {
        float id = inv_deg[nd];
        uint4 o;
        o.x = (uint32_t)f2bf(a[0] * id) | ((uint32_t)f2bf(a[1] * id) << 16);
        o.y = (uint32_t)f2bf(a[2] * id) | ((uint32_t)f2bf(a[3] * id) << 16);
        o.z = (uint32_t)f2bf(a[4] * id) | ((uint32_t)f2bf(a[5] * id) << 16);
        o.w = (uint32_t)f2bf(a[6] * id) | ((uint32_t)f2bf(a[7] * id) << 16);
        *(uint4*)&meanb[(size_t)node * HID + lane16 * 8] = o;
    }
}

// ---------------- layer: H = relu(mean@Wl + h@Wr + b), 64-node staged -----
// R12-verified (~39 us): 2x16KB staged tiles, 4 blk/CU, stage16 + XOR
// swizzle (chunk ^ row&7 on SOURCE + READ, rule #21), weights in VGPR,
// wave owns 32 cols x 64 nodes (acc[2][4]).
__global__ __launch_bounds__(256, 4) void layer_mfma(
    const unsigned short* __restrict__ Am,
    const unsigned short* __restrict__ Ah,
    const unsigned short* __restrict__ WlT,
    const unsigned short* __restrict__ WrT,
    const float* __restrict__ bias,
    unsigned short* __restrict__ Hout, int n) {
    __shared__ uint4 smA[64 * 16];   // 16 KiB: Am tile (swizzled content)
    __shared__ uint4 smB[64 * 16];   // 16 KiB: Ah tile
    int tid = threadIdx.x;
    int w = tid >> 6, L = tid & 63;
    int q = L >> 4, r16 = L & 15;
    int colbase = w << 5;            // wave owns 32 output cols
    int node0 = blockIdx.x * 64;

    // ---- stage both operand tiles: wave w covers KB-chunks w*4..w*4+3 ----
    {
        const unsigned short* srcs[2] = {Am, Ah};
#pragma unroll
        for (int op = 0; op < 2; ++op) {
            const unsigned short* S = srcs[op];
            char* D = (char*)(op ? smB : smA);
#pragma unroll
            for (int i = 0; i < 4; ++i) {
                int c = (w << 2) + i;              // KB index 0..15
                int row_l = (c << 2) + (L >> 4);   // local row 0..63
                int chunk = (L & 15) ^ (row_l & 7);
                const unsigned short* src =
                    S + (((size_t)(node0 + row_l)) << 7) + (chunk << 3);
                stage16(src, D + (c << 10));
            }
        }
    }

    // ---- preload weight fragments (L2-hot) under the staging drain ------
    short8 wfr[2][4][2];
#pragma unroll
    for (int seg = 0; seg < 2; ++seg) {
        const unsigned short* WT = seg ? WrT : WlT;
#pragma unroll
        for (int t = 0; t < 4; ++t)
#pragma unroll
            for (int i = 0; i < 2; ++i)
                wfr[seg][t][i] =
                    *(const short8*)&WT[(colbase + i * 16 + r16) * HID + t * 32 + q * 8];
    }

    __syncthreads();   // drains vmcnt(0): staged tiles + weights all ready

    v4f acc[2][4];
#pragma unroll
    for (int i = 0; i < 2; ++i)
#pragma unroll
        for (int j = 0; j < 4; ++j)
#pragma unroll
            for (int r = 0; r < 4; ++r) acc[i][j][r] = 0.f;

#pragma unroll
    for (int seg = 0; seg < 2; ++seg) {
        const uint4* SM = seg ? smB : smA;
#pragma unroll
        for (int t = 0; t < 4; ++t) {
            short8 bfr[4];
#pragma unroll
            for (int j = 0; j < 4; ++j) {
                int row = j * 16 + r16;
                bfr[j] = *(const short8*)&SM[(row << 4) + ((t * 4 + q) ^ (row & 7))];
            }
#pragma unroll
            for (int i = 0; i < 2; ++i)
#pragma unroll
                for (int j = 0; j < 4; ++j)
                    acc[i][j] = __builtin_amdgcn_mfma_f32_16x16x32_bf16(
                        wfr[seg][t][i], bfr[j], acc[i][j], 0, 0, 0);
        }
    }

#pragma unroll
    for (int i = 0; i < 2; ++i) {
        int col = colbase + i * 16 + q * 4;
        float4 bv = *(const float4*)&bias[col];
#pragma unroll
        for (int j = 0; j < 4; ++j) {
            int node = node0 + j * 16 + r16;
            if (node < n) {
                float v0 = acc[i][j][0] + bv.x;
                float v1 = acc[i][j][1] + bv.y;
                float v2 = acc[i][j][2] + bv.z;
                float v3 = acc[i][j][3] + bv.w;
                ushort4v o;
                o[0] = f2bf(v0 > 0.f ? v0 : 0.f);
                o[1] = f2bf(v1 > 0.f ? v1 : 0.f);
                o[2] = f2bf(v2 > 0.f ? v2 : 0.f);
                o[3] = f2bf(v3 > 0.f ? v3 : 0.f);
                *(ushort4v*)&Hout[(size_t)node * HID + col] = o;
            }
        }
    }
}

// ---------------- layer 3 + FC fused, fully staged, 128-tile --------------
// R17-verified (double-banked fcT prefetch recovered >=6us). Unchanged.
__global__ __launch_bounds__(256, 2) void layer3_fc(
    const unsigned short* __restrict__ Am,
    const unsigned short* __restrict__ Ah,
    const unsigned short* __restrict__ WlT,
    const unsigned short* __restrict__ WrT,
    const float* __restrict__ bias,
    const unsigned short* __restrict__ hA,
    const unsigned short* __restrict__ fcT,
    const float* __restrict__ fc_b,
    float* __restrict__ out, int n) {
    __shared__ uint4 smA[128 * 16];   // Am tile -> later H3 tile
    __shared__ uint4 smB[128 * 16];   // Ah tile == hB tile (reused by FC)
    int tid = threadIdx.x;
    int w = tid >> 6, L = tid & 63;
    int q = L >> 4, r16 = L & 15;
    int colbase = (w & 1) * 64;
    int nodebase = (w >> 1) * 64;
    int node0 = blockIdx.x * 128;

    // ---- stage Am + Ah tiles ----
    {
        const unsigned short* srcs[2] = {Am, Ah};
#pragma unroll
        for (int op = 0; op < 2; ++op) {
            const unsigned short* S = srcs[op];
            char* D = (char*)(op ? smB : smA);
#pragma unroll
            for (int i = 0; i < 8; ++i) {
                int c = (w << 3) + i;
                int row_l = (c << 2) + (L >> 4);
                int chunk = (L & 15) ^ (row_l & 7);
                const unsigned short* src =
                    S + (((size_t)(node0 + row_l)) << 7) + (chunk << 3);
                stage16(src, D + (c << 10));
            }
        }
    }

    short8 wfr[2][4][4];
#pragma unroll
    for (int seg = 0; seg < 2; ++seg) {
        const unsigned short* WT = seg ? WrT : WlT;
#pragma unroll
        for (int t = 0; t < 4; ++t)
#pragma unroll
            for (int i = 0; i < 4; ++i)
                wfr[seg][t][i] =
                    *(const short8*)&WT[(colbase + i * 16 + r16) * HID + t * 32 + q * 8];
    }

    __syncthreads();   // staged tiles + weights ready

    v4f acc[4][4];
#pragma unroll
    for (int i = 0; i < 4; ++i)
#pragma unroll
        for (int j = 0; j < 4; ++j)
#pragma unroll
            for (int r = 0; r < 4; ++r) acc[i][j][r] = 0.f;

#pragma unroll
    for (int seg = 0; seg < 2; ++seg) {
        const uint4* SM = seg ? smB : smA;
#pragma unroll
        for (int t = 0; t < 4; ++t) {
            short8 bfr[4];
#pragma unroll
            for (int j = 0; j < 4; ++j) {
                int row = nodebase + j * 16 + r16;
                bfr[j] = *(const short8*)&SM[(row << 4) + ((t * 4 + q) ^ (row & 7))];
            }
#pragma unroll
            for (int i = 0; i < 4; ++i)
#pragma unroll
                for (int j = 0; j < 4; ++j)
                    acc[i][j] = __builtin_amdgcn_mfma_f32_16x16x32_bf16(
                        wfr[seg][t][i], bfr[j], acc[i][j], 0, 0, 0);
        }
    }

    // ---- preload FC l=0 (hA) fragments + l=0 fcT bank: issued early ------
    int nd2[2], gvalid[2];
#pragma unroll
    for (int j = 0; j < 2; ++j) {
        int t = node0 + w * 32 + j * 16 + r16;
        gvalid[j] = t < n;
        nd2[j] = gvalid[j] ? t : n - 1;
    }
    short8 ha[2][4];
#pragma unroll
    for (int j = 0; j < 2; ++j)
#pragma unroll
        for (int t = 0; t < 4; ++t)
            ha[j][t] = *(const short8*)&hA[(size_t)nd2[j] * HID + t * 32 + q * 8];

    short8 afA[4][4], afB[4][4];     // double-banked fcT fragments
    const unsigned short* F0 = fcT;
    const unsigned short* F1 = fcT + (size_t)OUT_DIM * HID;
    const unsigned short* F2 = fcT + (size_t)2 * OUT_DIM * HID;
#pragma unroll
    for (int t = 0; t < 4; ++t)
#pragma unroll
        for (int i = 0; i < 4; ++i)
            afA[t][i] = *(const short8*)&F0[(i * 16 + r16) * HID + t * 32 + q * 8];

    __syncthreads();   // all smA GEMM reads done before H3 overwrite

    // ---- epilogue: relu'd H3 -> smA (swizzled, proven layout) ----
#pragma unroll
    for (int i = 0; i < 4; ++i) {
        int col = colbase + i * 16 + q * 4;
        float4 bv = *(const float4*)&bias[col];
#pragma unroll
        for (int j = 0; j < 4; ++j) {
            int row = nodebase + j * 16 + r16;
            float v0 = acc[i][j][0] + bv.x;
            float v1 = acc[i][j][1] + bv.y;
            float v2 = acc[i][j][2] + bv.z;
            float v3 = acc[i][j][3] + bv.w;
            uint2 val;
            val.x = (uint32_t)f2bf(v0 > 0.f ? v0 : 0.f) |
                    ((uint32_t)f2bf(v1 > 0.f ? v1 : 0.f) << 16);
            val.y = (uint32_t)f2bf(v2 > 0.f ? v2 : 0.f) |
                    ((uint32_t)f2bf(v3 > 0.f ? v3 : 0.f) << 16);
            int slot = (col >> 3) ^ (row & 7);
            uint2* p2 = (uint2*)&smA[(row << 4) + slot];
            p2[q & 1] = val;   // 8B half-chunk
        }
    }
    __syncthreads();

    // ---- FC: out[128 x 64] = [hA hB H3]@fcT + fc_b; wave w owns 32 rows --
    v4f acc2[4][2];
#pragma unroll
    for (int i = 0; i < 4; ++i) {
        float4 bv = *(const float4*)&fc_b[i * 16 + q * 4];
#pragma unroll
        for (int j = 0; j < 2; ++j) {
            acc2[i][j][0] = bv.x; acc2[i][j][1] = bv.y;
            acc2[i][j][2] = bv.z; acc2[i][j][3] = bv.w;
        }
    }

    // l=0: issue l=1 bank first, then MFMA with bank A (ha operands)
#pragma unroll
    for (int t = 0; t < 4; ++t)
#pragma unroll
        for (int i = 0; i < 4; ++i)
            afB[t][i] = *(const short8*)&F1[(i * 16 + r16) * HID + t * 32 + q * 8];
#pragma unroll
    for (int t = 0; t < 4; ++t)
#pragma unroll
        for (int i = 0; i < 4; ++i)
#pragma unroll
            for (int j = 0; j < 2; ++j)
                acc2[i][j] = __builtin_amdgcn_mfma_f32_16x16x32_bf16(
                    afA[t][i], ha[j][t], acc2[i][j], 0, 0, 0);

    // l=1: issue l=2 bank first, then MFMA with bank B (smB operands)
#pragma unroll
    for (int t = 0; t < 4; ++t)
#pragma unroll
        for (int i = 0; i < 4; ++i)
            afA[t][i] = *(const short8*)&F2[(i * 16 + r16) * HID + t * 32 + q * 8];
#pragma unroll
    for (int t = 0; t < 4; ++t) {
        short8 bfr[2];
#pragma unroll
        for (int j = 0; j < 2; ++j) {
            int row = w * 32 + j * 16 + r16;
            bfr[j] = *(const short8*)&smB[(row << 4) + ((t * 4 + q) ^ (row & 7))];
        }
#pragma unroll
        for (int i = 0; i < 4; ++i)
#pragma unroll
            for (int j = 0; j < 2; ++j)
                acc2[i][j] = __builtin_amdgcn_mfma_f32_16x16x32_bf16(
                    afB[t][i], bfr[j], acc2[i][j], 0, 0, 0);
    }

    // l=2: MFMA with bank A (smA/H3 operands)
#pragma unroll
    for (int t = 0; t < 4; ++t) {
        short8 bfr[2];
#pragma unroll
        for (int j = 0; j < 2; ++j) {
            int row = w * 32 + j * 16 + r16;
            bfr[j] = *(const short8*)&smA[(row << 4) + ((t * 4 + q) ^ (row & 7))];
        }
#pragma unroll
        for (int i = 0; i < 4; ++i)
#pragma unroll
            for (int j = 0; j < 2; ++j)
                acc2[i][j] = __builtin_amdgcn_mfma_f32_16x16x32_bf16(
                    afA[t][i], bfr[j], acc2[i][j], 0, 0, 0);
    }

#pragma unroll
    for (int i = 0; i < 4; ++i)
#pragma unroll
        for (int j = 0; j < 2; ++j)
            if (gvalid[j])
                *(v4f*)&out[(size_t)nd2[j] * OUT_DIM + i * 16 + q * 4] = acc2[i][j];
}

extern "C" void kernel_launch(void* const* d_in, const int* in_sizes, int n_in,
                              void* d_out, int out_size, void* d_ws, size_t ws_size,
                              hipStream_t stream) {
    const float* x     = (const float*)d_in[0];
    const int*   edges = (const int*)d_in[1];
    const float* Wl    = (const float*)d_in[2];
    const float* Wr    = (const float*)d_in[3];
    const float* b     = (const float*)d_in[4];
    const float* fc_w  = (const float*)d_in[5];
    const float* fc_b  = (const float*)d_in[6];
    float* out = (float*)d_out;

    char* ws = (char*)d_ws;
    size_t off = 0;
    auto alloc = [&](size_t bytes) {
        void* p = ws + off;
        off = (off + bytes + 255) & ~(size_t)255;
        return p;
    };
    int*   bin_cnt = (int*)alloc((size_t)NBIN2 * CNT_STRIDE * 4);
    int*   deg     = (int*)alloc((size_t)N_NODES * 4);
    float* inv_deg = (float*)alloc((size_t)N_NODES * 4);
    int*   ell     = (int*)alloc(((size_t)N_NODES * CAP + 64) * 4);
    unsigned int* bins = (unsigned int*)alloc((size_t)NBIN2 * BINCAP * 4);  // 12.8 MB
    // +128 rows: zeroed sentinel row + staged-tile overrun slack.
    unsigned short* xb    = (unsigned short*)alloc((size_t)(N_NODES + 128) * HID * 2);
    unsigned short* meanb = (unsigned short*)alloc((size_t)(N_NODES + 128) * HID * 2);
    unsigned short* hA    = (unsigned short*)alloc((size_t)(N_NODES + 128) * HID * 2);
    unsigned short* hB    = (unsigned short*)alloc((size_t)(N_NODES + 128) * HID * 2);
    unsigned short* WlT   = (unsigned short*)alloc((size_t)N_LAYERS * HID * HID * 2);
    unsigned short* WrT   = (unsigned short*)alloc((size_t)N_LAYERS * HID * HID * 2);
    unsigned short* fcT   = (unsigned short*)alloc((size_t)N_LAYERS * OUT_DIM * HID * 2);

    hipMemsetAsync(bin_cnt, 0, (size_t)NBIN2 * CNT_STRIDE * 4, stream);

    const int PREP_TOTAL = CONV_N + N_LAYERS * HID * HID + N_LAYERS * HID * OUT_DIM;
    int pregrid = (PREP_TOTAL + 255) / 256;   // 12788 > P1_BLOCKS+1
    merged_pre<<<pregrid, 256, 0, stream>>>(
        edges, bin_cnt, bins, x, xb, Wl, Wr, fc_w, WlT, WrT, fcT, xb, hA, hB);
    fill_p2<<<NBIN2 * 2, 256, 0, stream>>>(bin_cnt, bins, ell, deg, inv_deg, N_NODES);

    int lgrid = (N_NODES + 63) / 64;      // 1563
    int fgrid = (N_NODES + 127) / 128;    // 782
    int agrid = (N_NODES + 3) / 4;        // 25000 (1-wave blocks)

    agg_bf<<<agrid, 64, 0, stream>>>(xb, ell, deg, inv_deg, meanb);
    layer_mfma<<<lgrid, 256, 0, stream>>>(
        meanb, xb, WlT, WrT, b, hA, N_NODES);

    agg_bf<<<agrid, 64, 0, stream>>>(hA, ell, deg, inv_deg, meanb);
    layer_mfma<<<lgrid, 256, 0, stream>>>(
        meanb, hA, WlT + (size_t)HID * HID, WrT + (size_t)HID * HID, b + HID, hB, N_NODES);

    agg_bf<<<agrid, 64, 0, stream>>>(hB, ell, deg, inv_deg, meanb);
    layer3_fc<<<fgrid, 256, 0, stream>>>(
        meanb, hB, WlT + (size_t)2 * HID * HID, WrT + (size_t)2 * HID * HID, b + 2 * HID,
        hA, fcT, fc_b, out, N_NODES);
}

// Round 21
// 403.324 us; speedup vs baseline: 1.0160x; 1.0160x over previous
//
#include <hip/hip_runtime.h>
#include <hip/hip_bf16.h>
#include <stdint.h>

#define N_NODES 100000
#define N_EDGES 1600000
#define HID 128
#define OUT_DIM 64
#define N_LAYERS 3
#define CAP 64        // ELL row capacity (slots per node); deg~Poisson(16)
#define CAP_SHIFT 6
#define BIN_NODES 256 // dst nodes per bin (phase-1 packing granule)
#define NBIN2 ((N_NODES + BIN_NODES - 1) / BIN_NODES)   // 391
#define BINCAP 8192   // u32 edge slots per bin (mean ~4092, Poisson-tight)
#define CNT_STRIDE 16 // bin_cnt padded: one counter per 64B line (no false sharing)
#define EPT 32        // edges per thread in fill phase (8192/block)
#define P1_BLOCKS ((N_EDGES + 256 * EPT - 1) / (256 * EPT))   // 196

typedef __attribute__((ext_vector_type(8))) short short8;
typedef __attribute__((ext_vector_type(4))) float v4f;
typedef __attribute__((ext_vector_type(4))) unsigned short ushort4v;

__device__ __forceinline__ float bf2f(unsigned int lo16) {
    union { unsigned int i; float f; } v; v.i = lo16 << 16; return v.f;
}
__device__ __forceinline__ unsigned short f2bf(float f) {
    union { float f; unsigned int i; } v; v.f = f;
    unsigned int r = v.i + 0x7fffu + ((v.i >> 16) & 1u);  // RNE
    return (unsigned short)(r >> 16);
}

// async global->LDS, 16B per lane; LDS dest = wave-uniform base + lane*16,
// global src is per-lane (rule #21: swizzle goes on the SOURCE + the READ).
__device__ __forceinline__ void stage16(const void* g, void* l) {
    __builtin_amdgcn_global_load_lds(
        (const __attribute__((address_space(1))) unsigned int*)g,
        (__attribute__((address_space(3))) unsigned int*)l, 16, 0, 0);
}

// ---------------- merged prologue + fill phase 1 --------------------------
// R17-verified: EPT32 + line-padded bin_cnt (atomic-chain + false-sharing
// fixes totaled -19.7us over R16/R17).
#define CONV_N (N_NODES * HID / 4)
__global__ __launch_bounds__(256) void merged_pre(
    const int* __restrict__ raw,
    int* __restrict__ bin_cnt, unsigned int* __restrict__ bins,
    const float* __restrict__ x, unsigned short* __restrict__ xb,
    const float* __restrict__ Wl, const float* __restrict__ Wr,
    const float* __restrict__ fc_w,
    unsigned short* __restrict__ WlT, unsigned short* __restrict__ WrT,
    unsigned short* __restrict__ fcT,
    unsigned short* b0, unsigned short* b1, unsigned short* b2) {
    __shared__ int h[NBIN2];
    __shared__ int basekeep[NBIN2];
    __shared__ int sflag;
    int blk = blockIdx.x, tid = threadIdx.x;

    if (blk < P1_BLOCKS) {
        if (tid < 64) {
            int v = raw[2 * tid + 1];           // odd dwords = int64 high words
            unsigned long long bl = __ballot(v != 0);
            if (tid == 0) sflag = (bl == 0ull) ? 1 : 0;
        }
        for (int b = tid; b < NBIN2; b += 256) h[b] = 0;
        __syncthreads();
        bool is64 = (sflag != 0);

        int e0 = blk * (256 * EPT) + tid;
        int s[EPT], d[EPT];
#pragma unroll
        for (int k = 0; k < EPT; ++k) {
            int e = e0 + k * 256;
            if (e < N_EDGES) {
                if (is64) {
                    const long long* r = (const long long*)raw;
                    d[k] = (int)r[N_EDGES + e];
                    s[k] = (int)r[e];
                } else {
                    d[k] = raw[N_EDGES + e];
                    s[k] = raw[e];
                }
            } else {
                d[k] = -1;
            }
        }
#pragma unroll
        for (int k = 0; k < EPT; ++k)
            if (d[k] >= 0) atomicAdd(&h[d[k] >> 8], 1);
        __syncthreads();
        for (int b = tid; b < NBIN2; b += 256) {
            int c = h[b];
            basekeep[b] = c ? atomicAdd(&bin_cnt[b * CNT_STRIDE], c) : 0;
            h[b] = 0;   // reuse as block-local write cursor
        }
        __syncthreads();
#pragma unroll
        for (int k = 0; k < EPT; ++k) {
            if (d[k] >= 0) {
                int b = d[k] >> 8;
                int off = basekeep[b] + atomicAdd(&h[b], 1);
                if (off < BINCAP)
                    bins[(size_t)b * BINCAP + off] =
                        ((unsigned int)s[k] << 8) | (unsigned int)(d[k] & 255);
            }
        }
    }

    if (blk == P1_BLOCKS && tid < 192) {        // zero sentinel rows
        unsigned short* bufs[3] = {b0, b1, b2};
        uint32_t* p = (uint32_t*)bufs[tid >> 6];
        p[(size_t)N_NODES * 64 + (tid & 63)] = 0;
    }

    // ---- prep range (all blocks) ----
    int gidx = blk * 256 + tid;
    if (gidx < CONV_N) {
        float4 v = ((const float4*)x)[gidx];
        ushort4v o;
        o[0] = f2bf(v.x); o[1] = f2bf(v.y); o[2] = f2bf(v.z); o[3] = f2bf(v.w);
        ((ushort4v*)xb)[gidx] = o;
    } else {
        int idx = gidx - CONV_N;
        const int WELEMS = N_LAYERS * HID * HID;
        if (idx < WELEMS) {
            int l = idx / (HID * HID);
            int rem = idx - l * HID * HID;
            int k = rem / HID, nn2 = rem - k * HID;
            WlT[l * HID * HID + nn2 * HID + k] = f2bf(Wl[idx]);
            WrT[l * HID * HID + nn2 * HID + k] = f2bf(Wr[idx]);
        } else {
            int j = idx - WELEMS;
            if (j < N_LAYERS * HID * OUT_DIM) {
                int l = j / (HID * OUT_DIM);
                int rem = j - l * HID * OUT_DIM;
                int k = rem / OUT_DIM, o = rem - k * OUT_DIM;
                fcT[l * OUT_DIM * HID + o * HID + k] = f2bf(fc_w[(l * HID + k) * OUT_DIM + o]);
            }
        }
    }
}

// ---------------- fill phase 2: dst-partitioned ELL build in LDS ----------
// Half-bin split (R18/R19, neutral-verified): each block owns 128 nodes
// (32 KB tile, 782 blocks). Both halves scan the full bin segment in the
// SAME order and keep matching edges -> ELL content bit-identical.
__global__ __launch_bounds__(256) void fill_p2(const int* __restrict__ bin_cnt,
                                               const unsigned int* __restrict__ bins,
                                               int* __restrict__ ell,
                                               int* __restrict__ deg,
                                               float* __restrict__ inv_deg, int n) {
    __shared__ int tile[128 * CAP];   // 32 KB
    __shared__ int cnt[128];
    int blk = blockIdx.x, tid = threadIdx.x;
    int b = blk >> 1, half = blk & 1;
    for (int i = tid; i < 128; i += 256) cnt[i] = 0;
    __syncthreads();

    int m = bin_cnt[b * CNT_STRIDE];
    if (m > BINCAP) m = BINCAP;
    for (int i = tid; i < m; i += 256) {
        unsigned int e = bins[(size_t)b * BINCAP + i];
        int dl = (int)(e & 255u);
        if ((dl >> 7) == half) {
            int r = dl & 127;
            int slot = atomicAdd(&cnt[r], 1);
            if (slot < CAP) tile[(r << CAP_SHIFT) + slot] = (int)(e >> 8);
        }
    }
    __syncthreads();

    int node0 = (b << 8) + (half << 7);
    for (int i = tid; i < 128; i += 256) {
        int node = node0 + i;
        if (node < n) {
            int dgf = cnt[i];
            int dg = dgf > CAP ? CAP : dgf;
            deg[node] = dg;
            inv_deg[node] = 1.0f / (float)(dg > 0 ? dg : 1);
            int r = (dg + 7) & ~7;
            for (int p = dg; p < r; ++p) tile[(i << CAP_SHIFT) + p] = N_NODES;
        }
    }
    __syncthreads();

    const uint4* t4 = (const uint4*)tile;    // row = 16 uint4
    uint4* g4 = (uint4*)ell;
    for (int v = tid; v < 128 * 16; v += 256) {
        int row = v >> 4;
        int node = node0 + row;
        if (node < n) g4[((size_t)node << 4) + (v & 15)] = t4[v];
    }
}

// ---------------- mean aggregation: 16 nodes/block, 16 lanes/node ---------
// FINAL form: R0's 256-thread structure (57.1-57.7us, 3.67 TB/s, VGPR 44,
// occ ~43%), reproduced 8x. R20's 1-wave-block probe was null (occ
// unchanged, +1.5% FETCH): the ~13.5-wave cap is the MEMORY SYSTEM's
// outstanding-request limit on the random-gather path, not any software
// occupancy constraint. All eight levers tested (MLP up x3, block size
// up/down, pipelining x2, cache hints); this is the operating point.
__global__ __launch_bounds__(256) void agg_bf(
    const unsigned short* __restrict__ h, const int* __restrict__ ell,
    const int* __restrict__ deg, const float* __restrict__ inv_deg,
    unsigned short* __restrict__ meanb) {
    int tid = threadIdx.x;
    int grp = tid >> 4;          // node slot in block (0..15)
    int lane16 = tid & 15;       // channel octet
    int node = blockIdx.x * 16 + grp;
    bool valid = node < N_NODES;
    int nd = valid ? node : 0;
    int dg = valid ? deg[nd] : 0;
    int dgp = (dg + 7) & ~7;
    int base = nd << CAP_SHIFT;
    const uint4* hv = (const uint4*)h;   // row = 16 uint4
    float a[8];
#pragma unroll
    for (int c = 0; c < 8; ++c) a[c] = 0.f;

    for (int t = 0; t < dgp; t += 8) {
        int idx[8];
#pragma unroll
        for (int u = 0; u < 8; ++u) idx[u] = ell[base + t + u];
        uint4 v[8];
#pragma unroll
        for (int u = 0; u < 8; ++u) v[u] = hv[(size_t)idx[u] * 16 + lane16];
#pragma unroll
        for (int u = 0; u < 8; ++u) {
            a[0] += bf2f(v[u].x & 0xffffu); a[1] += bf2f(v[u].x >> 16);
            a[2] += bf2f(v[u].y & 0xffffu); a[3] += bf2f(v[u].y >> 16);
            a[4] += bf2f(v[u].z & 0xffffu); a[5] += bf2f(v[u].z >> 16);
            a[6] += bf2f(v[u].w & 0xffffu); a[7] += bf2f(v[u].w >> 16);
        }
    }
    if (valid) {
        float id = inv_deg[nd];
        uint4 o;
        o.x = (uint32_t)f2bf(a[0] * id) | ((uint32_t)f2bf(a[1] * id) << 16);
        o.y = (uint32_t)f2bf(a[2] * id) | ((uint32_t)f2bf(a[3] * id) << 16);
        o.z = (uint32_t)f2bf(a[4] * id) | ((uint32_t)f2bf(a[5] * id) << 16);
        o.w = (uint32_t)f2bf(a[6] * id) | ((uint32_t)f2bf(a[7] * id) << 16);
        *(uint4*)&meanb[(size_t)node * HID + lane16 * 8] = o;
    }
}

// ---------------- layer: H = relu(mean@Wl + h@Wr + b), 64-node staged -----
// R12-verified (~39 us): 2x16KB staged tiles, 4 blk/CU, stage16 + XOR
// swizzle (chunk ^ row&7 on SOURCE + READ, rule #21), weights in VGPR,
// wave owns 32 cols x 64 nodes (acc[2][4]).
__global__ __launch_bounds__(256, 4) void layer_mfma(
    const unsigned short* __restrict__ Am,
    const unsigned short* __restrict__ Ah,
    const unsigned short* __restrict__ WlT,
    const unsigned short* __restrict__ WrT,
    const float* __restrict__ bias,
    unsigned short* __restrict__ Hout, int n) {
    __shared__ uint4 smA[64 * 16];   // 16 KiB: Am tile (swizzled content)
    __shared__ uint4 smB[64 * 16];   // 16 KiB: Ah tile
    int tid = threadIdx.x;
    int w = tid >> 6, L = tid & 63;
    int q = L >> 4, r16 = L & 15;
    int colbase = w << 5;            // wave owns 32 output cols
    int node0 = blockIdx.x * 64;

    // ---- stage both operand tiles: wave w covers KB-chunks w*4..w*4+3 ----
    {
        const unsigned short* srcs[2] = {Am, Ah};
#pragma unroll
        for (int op = 0; op < 2; ++op) {
            const unsigned short* S = srcs[op];
            char* D = (char*)(op ? smB : smA);
#pragma unroll
            for (int i = 0; i < 4; ++i) {
                int c = (w << 2) + i;              // KB index 0..15
                int row_l = (c << 2) + (L >> 4);   // local row 0..63
                int chunk = (L & 15) ^ (row_l & 7);
                const unsigned short* src =
                    S + (((size_t)(node0 + row_l)) << 7) + (chunk << 3);
                stage16(src, D + (c << 10));
            }
        }
    }

    // ---- preload weight fragments (L2-hot) under the staging drain ------
    short8 wfr[2][4][2];
#pragma unroll
    for (int seg = 0; seg < 2; ++seg) {
        const unsigned short* WT = seg ? WrT : WlT;
#pragma unroll
        for (int t = 0; t < 4; ++t)
#pragma unroll
            for (int i = 0; i < 2; ++i)
                wfr[seg][t][i] =
                    *(const short8*)&WT[(colbase + i * 16 + r16) * HID + t * 32 + q * 8];
    }

    __syncthreads();   // drains vmcnt(0): staged tiles + weights all ready

    v4f acc[2][4];
#pragma unroll
    for (int i = 0; i < 2; ++i)
#pragma unroll
        for (int j = 0; j < 4; ++j)
#pragma unroll
            for (int r = 0; r < 4; ++r) acc[i][j][r] = 0.f;

#pragma unroll
    for (int seg = 0; seg < 2; ++seg) {
        const uint4* SM = seg ? smB : smA;
#pragma unroll
        for (int t = 0; t < 4; ++t) {
            short8 bfr[4];
#pragma unroll
            for (int j = 0; j < 4; ++j) {
                int row = j * 16 + r16;
                bfr[j] = *(const short8*)&SM[(row << 4) + ((t * 4 + q) ^ (row & 7))];
            }
#pragma unroll
            for (int i = 0; i < 2; ++i)
#pragma unroll
                for (int j = 0; j < 4; ++j)
                    acc[i][j] = __builtin_amdgcn_mfma_f32_16x16x32_bf16(
                        wfr[seg][t][i], bfr[j], acc[i][j], 0, 0, 0);
        }
    }

#pragma unroll
    for (int i = 0; i < 2; ++i) {
        int col = colbase + i * 16 + q * 4;
        float4 bv = *(const float4*)&bias[col];
#pragma unroll
        for (int j = 0; j < 4; ++j) {
            int node = node0 + j * 16 + r16;
            if (node < n) {
                float v0 = acc[i][j][0] + bv.x;
                float v1 = acc[i][j][1] + bv.y;
                float v2 = acc[i][j][2] + bv.z;
                float v3 = acc[i][j][3] + bv.w;
                ushort4v o;
                o[0] = f2bf(v0 > 0.f ? v0 : 0.f);
                o[1] = f2bf(v1 > 0.f ? v1 : 0.f);
                o[2] = f2bf(v2 > 0.f ? v2 : 0.f);
                o[3] = f2bf(v3 > 0.f ? v3 : 0.f);
                *(ushort4v*)&Hout[(size_t)node * HID + col] = o;
            }
        }
    }
}

// ---------------- layer 3 + FC fused, fully staged, 128-tile --------------
// R17-verified (double-banked fcT prefetch recovered >=6us). Unchanged.
__global__ __launch_bounds__(256, 2) void layer3_fc(
    const unsigned short* __restrict__ Am,
    const unsigned short* __restrict__ Ah,
    const unsigned short* __restrict__ WlT,
    const unsigned short* __restrict__ WrT,
    const float* __restrict__ bias,
    const unsigned short* __restrict__ hA,
    const unsigned short* __restrict__ fcT,
    const float* __restrict__ fc_b,
    float* __restrict__ out, int n) {
    __shared__ uint4 smA[128 * 16];   // Am tile -> later H3 tile
    __shared__ uint4 smB[128 * 16];   // Ah tile == hB tile (reused by FC)
    int tid = threadIdx.x;
    int w = tid >> 6, L = tid & 63;
    int q = L >> 4, r16 = L & 15;
    int colbase = (w & 1) * 64;
    int nodebase = (w >> 1) * 64;
    int node0 = blockIdx.x * 128;

    // ---- stage Am + Ah tiles ----
    {
        const unsigned short* srcs[2] = {Am, Ah};
#pragma unroll
        for (int op = 0; op < 2; ++op) {
            const unsigned short* S = srcs[op];
            char* D = (char*)(op ? smB : smA);
#pragma unroll
            for (int i = 0; i < 8; ++i) {
                int c = (w << 3) + i;
                int row_l = (c << 2) + (L >> 4);
                int chunk = (L & 15) ^ (row_l & 7);
                const unsigned short* src =
                    S + (((size_t)(node0 + row_l)) << 7) + (chunk << 3);
                stage16(src, D + (c << 10));
            }
        }
    }

    short8 wfr[2][4][4];
#pragma unroll
    for (int seg = 0; seg < 2; ++seg) {
        const unsigned short* WT = seg ? WrT : WlT;
#pragma unroll
        for (int t = 0; t < 4; ++t)
#pragma unroll
            for (int i = 0; i < 4; ++i)
                wfr[seg][t][i] =
                    *(const short8*)&WT[(colbase + i * 16 + r16) * HID + t * 32 + q * 8];
    }

    __syncthreads();   // staged tiles + weights ready

    v4f acc[4][4];
#pragma unroll
    for (int i = 0; i < 4; ++i)
#pragma unroll
        for (int j = 0; j < 4; ++j)
#pragma unroll
            for (int r = 0; r < 4; ++r) acc[i][j][r] = 0.f;

#pragma unroll
    for (int seg = 0; seg < 2; ++seg) {
        const uint4* SM = seg ? smB : smA;
#pragma unroll
        for (int t = 0; t < 4; ++t) {
            short8 bfr[4];
#pragma unroll
            for (int j = 0; j < 4; ++j) {
                int row = nodebase + j * 16 + r16;
                bfr[j] = *(const short8*)&SM[(row << 4) + ((t * 4 + q) ^ (row & 7))];
            }
#pragma unroll
            for (int i = 0; i < 4; ++i)
#pragma unroll
                for (int j = 0; j < 4; ++j)
                    acc[i][j] = __builtin_amdgcn_mfma_f32_16x16x32_bf16(
                        wfr[seg][t][i], bfr[j], acc[i][j], 0, 0, 0);
        }
    }

    // ---- preload FC l=0 (hA) fragments + l=0 fcT bank: issued early ------
    int nd2[2], gvalid[2];
#pragma unroll
    for (int j = 0; j < 2; ++j) {
        int t = node0 + w * 32 + j * 16 + r16;
        gvalid[j] = t < n;
        nd2[j] = gvalid[j] ? t : n - 1;
    }
    short8 ha[2][4];
#pragma unroll
    for (int j = 0; j < 2; ++j)
#pragma unroll
        for (int t = 0; t < 4; ++t)
            ha[j][t] = *(const short8*)&hA[(size_t)nd2[j] * HID + t * 32 + q * 8];

    short8 afA[4][4], afB[4][4];     // double-banked fcT fragments
    const unsigned short* F0 = fcT;
    const unsigned short* F1 = fcT + (size_t)OUT_DIM * HID;
    const unsigned short* F2 = fcT + (size_t)2 * OUT_DIM * HID;
#pragma unroll
    for (int t = 0; t < 4; ++t)
#pragma unroll
        for (int i = 0; i < 4; ++i)
            afA[t][i] = *(const short8*)&F0[(i * 16 + r16) * HID + t * 32 + q * 8];

    __syncthreads();   // all smA GEMM reads done before H3 overwrite

    // ---- epilogue: relu'd H3 -> smA (swizzled, proven layout) ----
#pragma unroll
    for (int i = 0; i < 4; ++i) {
        int col = colbase + i * 16 + q * 4;
        float4 bv = *(const float4*)&bias[col];
#pragma unroll
        for (int j = 0; j < 4; ++j) {
            int row = nodebase + j * 16 + r16;
            float v0 = acc[i][j][0] + bv.x;
            float v1 = acc[i][j][1] + bv.y;
            float v2 = acc[i][j][2] + bv.z;
            float v3 = acc[i][j][3] + bv.w;
            uint2 val;
            val.x = (uint32_t)f2bf(v0 > 0.f ? v0 : 0.f) |
                    ((uint32_t)f2bf(v1 > 0.f ? v1 : 0.f) << 16);
            val.y = (uint32_t)f2bf(v2 > 0.f ? v2 : 0.f) |
                    ((uint32_t)f2bf(v3 > 0.f ? v3 : 0.f) << 16);
            int slot = (col >> 3) ^ (row & 7);
            uint2* p2 = (uint2*)&smA[(row << 4) + slot];
            p2[q & 1] = val;   // 8B half-chunk
        }
    }
    __syncthreads();

    // ---- FC: out[128 x 64] = [hA hB H3]@fcT + fc_b; wave w owns 32 rows --
    v4f acc2[4][2];
#pragma unroll
    for (int i = 0; i < 4; ++i) {
        float4 bv = *(const float4*)&fc_b[i * 16 + q * 4];
#pragma unroll
        for (int j = 0; j < 2; ++j) {
            acc2[i][j][0] = bv.x; acc2[i][j][1] = bv.y;
            acc2[i][j][2] = bv.z; acc2[i][j][3] = bv.w;
        }
    }

    // l=0: issue l=1 bank first, then MFMA with bank A (ha operands)
#pragma unroll
    for (int t = 0; t < 4; ++t)
#pragma unroll
        for (int i = 0; i < 4; ++i)
            afB[t][i] = *(const short8*)&F1[(i * 16 + r16) * HID + t * 32 + q * 8];
#pragma unroll
    for (int t = 0; t < 4; ++t)
#pragma unroll
        for (int i = 0; i < 4; ++i)
#pragma unroll
            for (int j = 0; j < 2; ++j)
                acc2[i][j] = __builtin_amdgcn_mfma_f32_16x16x32_bf16(
                    afA[t][i], ha[j][t], acc2[i][j], 0, 0, 0);

    // l=1: issue l=2 bank first, then MFMA with bank B (smB operands)
#pragma unroll
    for (int t = 0; t < 4; ++t)
#pragma unroll
        for (int i = 0; i < 4; ++i)
            afA[t][i] = *(const short8*)&F2[(i * 16 + r16) * HID + t * 32 + q * 8];
#pragma unroll
    for (int t = 0; t < 4; ++t) {
        short8 bfr[2];
#pragma unroll
        for (int j = 0; j < 2; ++j) {
            int row = w * 32 + j * 16 + r16;
            bfr[j] = *(const short8*)&smB[(row << 4) + ((t * 4 + q) ^ (row & 7))];
        }
#pragma unroll
        for (int i = 0; i < 4; ++i)
#pragma unroll
            for (int j = 0; j < 2; ++j)
                acc2[i][j] = __builtin_amdgcn_mfma_f32_16x16x32_bf16(
                    afB[t][i], bfr[j], acc2[i][j], 0, 0, 0);
    }

    // l=2: MFMA with bank A (smA/H3 operands)
#pragma unroll
    for (int t = 0; t < 4; ++t) {
        short8 bfr[2];
#pragma unroll
        for (int j = 0; j < 2; ++j) {
            int row = w * 32 + j * 16 + r16;
            bfr[j] = *(const short8*)&smA[(row << 4) + ((t * 4 + q) ^ (row & 7))];
        }
#pragma unroll
        for (int i = 0; i < 4; ++i)
#pragma unroll
            for (int j = 0; j < 2; ++j)
                acc2[i][j] = __builtin_amdgcn_mfma_f32_16x16x32_bf16(
                    afA[t][i], bfr[j], acc2[i][j], 0, 0, 0);
    }

#pragma unroll
    for (int i = 0; i < 4; ++i)
#pragma unroll
        for (int j = 0; j < 2; ++j)
            if (gvalid[j])
                *(v4f*)&out[(size_t)nd2[j] * OUT_DIM + i * 16 + q * 4] = acc2[i][j];
}

extern "C" void kernel_launch(void* const* d_in, const int* in_sizes, int n_in,
                              void* d_out, int out_size, void* d_ws, size_t ws_size,
                              hipStream_t stream) {
    const float* x     = (const float*)d_in[0];
    const int*   edges = (const int*)d_in[1];
    const float* Wl    = (const float*)d_in[2];
    const float* Wr    = (const float*)d_in[3];
    const float* b     = (const float*)d_in[4];
    const float* fc_w  = (const float*)d_in[5];
    const float* fc_b  = (const float*)d_in[6];
    float* out = (float*)d_out;

    char* ws = (char*)d_ws;
    size_t off = 0;
    auto alloc = [&](size_t bytes) {
        void* p = ws + off;
        off = (off + bytes + 255) & ~(size_t)255;
        return p;
    };
    int*   bin_cnt = (int*)alloc((size_t)NBIN2 * CNT_STRIDE * 4);
    int*   deg     = (int*)alloc((size_t)N_NODES * 4);
    float* inv_deg = (float*)alloc((size_t)N_NODES * 4);
    int*   ell     = (int*)alloc(((size_t)N_NODES * CAP + 64) * 4);
    unsigned int* bins = (unsigned int*)alloc((size_t)NBIN2 * BINCAP * 4);  // 12.8 MB
    // +128 rows: zeroed sentinel row + staged-tile overrun slack.
    unsigned short* xb    = (unsigned short*)alloc((size_t)(N_NODES + 128) * HID * 2);
    unsigned short* meanb = (unsigned short*)alloc((size_t)(N_NODES + 128) * HID * 2);
    unsigned short* hA    = (unsigned short*)alloc((size_t)(N_NODES + 128) * HID * 2);
    unsigned short* hB    = (unsigned short*)alloc((size_t)(N_NODES + 128) * HID * 2);
    unsigned short* WlT   = (unsigned short*)alloc((size_t)N_LAYERS * HID * HID * 2);
    unsigned short* WrT   = (unsigned short*)alloc((size_t)N_LAYERS * HID * HID * 2);
    unsigned short* fcT   = (unsigned short*)alloc((size_t)N_LAYERS * OUT_DIM * HID * 2);

    hipMemsetAsync(bin_cnt, 0, (size_t)NBIN2 * CNT_STRIDE * 4, stream);

    const int PREP_TOTAL = CONV_N + N_LAYERS * HID * HID + N_LAYERS * HID * OUT_DIM;
    int pregrid = (PREP_TOTAL + 255) / 256;   // 12788 > P1_BLOCKS+1
    merged_pre<<<pregrid, 256, 0, stream>>>(
        edges, bin_cnt, bins, x, xb, Wl, Wr, fc_w, WlT, WrT, fcT, xb, hA, hB);
    fill_p2<<<NBIN2 * 2, 256, 0, stream>>>(bin_cnt, bins, ell, deg, inv_deg, N_NODES);

    int lgrid = (N_NODES + 63) / 64;      // 1563
    int fgrid = (N_NODES + 127) / 128;    // 782
    int agrid = (N_NODES + 15) / 16;      // 6250

    agg_bf<<<agrid, 256, 0, stream>>>(xb, ell, deg, inv_deg, meanb);
    layer_mfma<<<lgrid, 256, 0, stream>>>(
        meanb, xb, WlT, WrT, b, hA, N_NODES);

    agg_bf<<<agrid, 256, 0, stream>>>(hA, ell, deg, inv_deg, meanb);
    layer_mfma<<<lgrid, 256, 0, stream>>>(
        meanb, hA, WlT + (size_t)HID * HID, WrT + (size_t)HID * HID, b + HID, hB, N_NODES);

    agg_bf<<<agrid, 256, 0, stream>>>(hB, ell, deg, inv_deg, meanb);
    layer3_fc<<<fgrid, 256, 0, stream>>>(
        meanb, hB, WlT + (size_t)2 * HID * HID, WrT + (size_t)2 * HID * HID, b + 2 * HID,
        hA, fcT, fc_b, out, N_NODES);
}